// Round 1
// baseline (792.653 us; speedup 1.0000x reference)
//
#include <hip/hip_runtime.h>

#define B  32
#define CD 128
#define O3 384
#define N  4096
#define H  4
#define C  32

__device__ __forceinline__ float dot4(const float4& a, const float4& b) {
  return a.x * b.x + a.y * b.y + a.z * b.z + a.w * b.w;
}

// ---------------------------------------------------------------------------
// K1: qkv 1x1 GEMM + bias, then 3-tap depthwise along y (w=1 => only the
// middle column of the 3x3 kernel touches real data) + bias -> qkvd.
// Block tile: 128 o  x 64 pre-columns (62 outputs + 2 halo). 128 threads,
// each computes an 8x8 register tile over K=128 in 16-chunks.
// grid (67, 3, 32)
// ---------------------------------------------------------------------------
__global__ __launch_bounds__(128) void k1_qkv_dw(
    const float* __restrict__ x, const float* __restrict__ qkv_w,
    const float* __restrict__ qkv_b, const float* __restrict__ dw_w,
    const float* __restrict__ dw_b, float* __restrict__ qkvd)
{
  __shared__ float Ws[16][132];   // Ws[kk][o], padded
  __shared__ float xs[16][64];    // xs[kk][cy]
  __shared__ float pres[128][68]; // pre-dw tile, padded for float alignment

  const int t = threadIdx.x;
  const int ytile = blockIdx.x, otile = blockIdx.y, b = blockIdx.z;
  const int obase = otile * 128;
  const int ybase = ytile * 62 - 1;          // global y of pre column 0
  const int to = t >> 3;                     // 16 groups of 8 o
  const int ty = t & 7;                      // 8 groups of 8 y

  float acc[8][8];
#pragma unroll
  for (int i = 0; i < 8; i++)
#pragma unroll
    for (int y = 0; y < 8; y++) acc[i][y] = 0.f;

  const float* xb = x + (size_t)b * CD * N;

  for (int k0 = 0; k0 < CD; k0 += 16) {
#pragma unroll
    for (int r = 0; r < 4; r++) {            // 512 float4 loads of W chunk
      int f = t + 128 * r;
      int o = f >> 2, kk0 = (f & 3) << 2;
      float4 w4 = *(const float4*)(qkv_w + (size_t)(obase + o) * CD + k0 + kk0);
      Ws[kk0 + 0][o] = w4.x; Ws[kk0 + 1][o] = w4.y;
      Ws[kk0 + 2][o] = w4.z; Ws[kk0 + 3][o] = w4.w;
    }
#pragma unroll
    for (int r = 0; r < 8; r++) {            // x chunk, coalesced along y
      int e = t + 128 * r;
      int kk = e >> 6, cy = e & 63;
      int yg = ybase + cy;
      xs[kk][cy] = (yg >= 0 && yg < N) ? xb[(size_t)(k0 + kk) * N + yg] : 0.f;
    }
    __syncthreads();
#pragma unroll
    for (int kk = 0; kk < 16; kk++) {
      float4 a0 = *(const float4*)&Ws[kk][to * 8];
      float4 a1 = *(const float4*)&Ws[kk][to * 8 + 4];
      float4 b0 = *(const float4*)&xs[kk][ty * 8];
      float4 b1 = *(const float4*)&xs[kk][ty * 8 + 4];
      float at[8] = {a0.x, a0.y, a0.z, a0.w, a1.x, a1.y, a1.z, a1.w};
      float bt[8] = {b0.x, b0.y, b0.z, b0.w, b1.x, b1.y, b1.z, b1.w};
#pragma unroll
      for (int i = 0; i < 8; i++)
#pragma unroll
        for (int y = 0; y < 8; y++) acc[i][y] += at[i] * bt[y];
    }
    __syncthreads();
  }

  // bias + stage pre-dw tile in LDS; zero columns outside [0,N) so the
  // depthwise sees the conv's zero padding AFTER the qkv bias was applied.
#pragma unroll
  for (int i = 0; i < 8; i++) {
    int o = to * 8 + i;
    float bias = qkv_b[obase + o];
#pragma unroll
    for (int y = 0; y < 8; y++) {
      int cy = ty * 8 + y;
      int yg = ybase + cy;
      pres[o][cy] = (yg >= 0 && yg < N) ? (acc[i][y] + bias) : 0.f;
    }
  }
  __syncthreads();

  // depthwise 3-tap (+ bias), coalesced store: lanes sweep y, o wave-uniform
  const int cy2 = t & 63, og = t >> 6;
  if (cy2 >= 1 && cy2 <= 62) {
    int yo = ybase + cy2;
    if (yo < N) {
      for (int r2 = 0; r2 < 64; r2++) {
        int o2 = og * 64 + r2;
        int oo = obase + o2;
        float w0 = dw_w[oo * 9 + 1];
        float w1 = dw_w[oo * 9 + 4];
        float w2 = dw_w[oo * 9 + 7];
        float v = w0 * pres[o2][cy2 - 1] + w1 * pres[o2][cy2] +
                  w2 * pres[o2][cy2 + 1] + dw_b[oo];
        qkvd[((size_t)b * O3 + oo) * N + yo] = v;
      }
    }
  }
}

// ---------------------------------------------------------------------------
// K3: raw QK^T Gram (32x32 per b,h) + per-row sum-of-squares for q,k.
// Direct global float4 reads (L1-served broadcasts), atomic accumulation.
// grid (4, H, B), 256 threads; each 64-lane group owns a 256-y slab,
// each lane owns a 4x4 (i,j) tile.
// ---------------------------------------------------------------------------
__global__ __launch_bounds__(256) void k3_attn(
    const float* __restrict__ qkvd, float* __restrict__ attnraw,
    float* __restrict__ sumsq)
{
  const int ytile = blockIdx.x, h = blockIdx.y, b = blockIdx.z;
  const int t = threadIdx.x;
  const int g = t >> 6, l = t & 63;
  const int i0 = ((l >> 3) & 7) * 4;
  const int j0 = (l & 7) * 4;
  const float* qb = qkvd + ((size_t)b * O3 + h * C) * N;
  const float* kb = qkvd + ((size_t)b * O3 + CD + h * C) * N;
  const int y0 = ytile * 1024 + g * 256;

  float acc[4][4];
#pragma unroll
  for (int ii = 0; ii < 4; ii++)
#pragma unroll
    for (int jj = 0; jj < 4; jj++) acc[ii][jj] = 0.f;
  float sq[4] = {0.f, 0.f, 0.f, 0.f};
  float sk[4] = {0.f, 0.f, 0.f, 0.f};

  for (int y = y0; y < y0 + 256; y += 4) {
    float4 qv[4], kv[4];
#pragma unroll
    for (int ii = 0; ii < 4; ii++)
      qv[ii] = *(const float4*)(qb + (size_t)(i0 + ii) * N + y);
#pragma unroll
    for (int jj = 0; jj < 4; jj++)
      kv[jj] = *(const float4*)(kb + (size_t)(j0 + jj) * N + y);
#pragma unroll
    for (int ii = 0; ii < 4; ii++)
#pragma unroll
      for (int jj = 0; jj < 4; jj++) acc[ii][jj] += dot4(qv[ii], kv[jj]);
    if (j0 == 0) {
#pragma unroll
      for (int ii = 0; ii < 4; ii++) sq[ii] += dot4(qv[ii], qv[ii]);
    }
    if (i0 == 0) {
#pragma unroll
      for (int jj = 0; jj < 4; jj++) sk[jj] += dot4(kv[jj], kv[jj]);
    }
  }

#pragma unroll
  for (int ii = 0; ii < 4; ii++)
#pragma unroll
    for (int jj = 0; jj < 4; jj++)
      atomicAdd(&attnraw[(((size_t)b * H + h) * C + i0 + ii) * C + j0 + jj],
                acc[ii][jj]);
  if (j0 == 0)
#pragma unroll
    for (int ii = 0; ii < 4; ii++)
      atomicAdd(&sumsq[b * 256 + h * C + i0 + ii], sq[ii]);
  if (i0 == 0)
#pragma unroll
    for (int jj = 0; jj < 4; jj++)
      atomicAdd(&sumsq[b * 256 + CD + h * C + j0 + jj], sk[jj]);
}

// ---------------------------------------------------------------------------
// K4: normalize attn, apply temperature, exact stable top-k rank per row,
// fold the 4 masked softmaxes into one combined weight matrix Awt.
// Rank r_j = #{v > v_j} + #{v == v_j, idx < j}  (matches jax.lax.top_k ties).
// Included in top-k iff r_j < k. Row max is always included (rank 0).
// grid (H, B), 64 threads (lanes 0..31 active for the per-row work)
// ---------------------------------------------------------------------------
__global__ void k4_post(
    const float* __restrict__ attnraw, const float* __restrict__ sumsq,
    const float* __restrict__ temperature, const float* __restrict__ attn_w,
    float* __restrict__ Awt)
{
  __shared__ float La[32][33];
  __shared__ float Le[32][33];
  __shared__ int   Lr[32][32];
  __shared__ float rq[32], rk[32];
  const int h = blockIdx.x, b = blockIdx.y, t = threadIdx.x;

  if (t < 32)
    rq[t] = 1.f / fmaxf(sqrtf(sumsq[b * 256 + h * C + t]), 1e-12f);
  else if (t < 64)
    rk[t - 32] = 1.f / fmaxf(sqrtf(sumsq[b * 256 + CD + h * C + (t - 32)]), 1e-12f);
  __syncthreads();

  const float temp = temperature[h];
  const float* ar = attnraw + ((size_t)b * H + h) * C * C;
  for (int e = t; e < C * C; e += 64) {
    int i = e >> 5, j = e & 31;
    La[i][j] = ar[e] * rq[i] * rk[j] * temp;
  }
  __syncthreads();

  if (t < 32) {
    const int i = t;
    float m = -1e30f;
    for (int j = 0; j < 32; j++) m = fmaxf(m, La[i][j]);
    float S0 = 0.f, S1 = 0.f, S2 = 0.f, S3 = 0.f;
    for (int j = 0; j < 32; j++) {
      float v = La[i][j];
      int r = 0;
      for (int j2 = 0; j2 < 32; j2++) {
        float v2 = La[i][j2];
        r += (v2 > v) || (v2 == v && j2 < j);
      }
      float e = expf(v - m);
      Le[i][j] = e;
      Lr[i][j] = r;
      if (r < 16) S0 += e;
      if (r < 21) S1 += e;
      if (r < 24) S2 += e;
      if (r < 25) S3 += e;
    }
    float w0 = attn_w[0] / S0, w1 = attn_w[1] / S1;
    float w2 = attn_w[2] / S2, w3 = attn_w[3] / S3;
    for (int j = 0; j < 32; j++) {
      int r = Lr[i][j];
      float cmb = (r < 16 ? w0 : 0.f) + (r < 21 ? w1 : 0.f) +
                  (r < 24 ? w2 : 0.f) + (r < 25 ? w3 : 0.f);
      Awt[(((size_t)b * H + h) * C + i) * C + j] = Le[i][j] * cmb;
    }
  }
}

// ---------------------------------------------------------------------------
// K5: M_b = proj_w @ blockdiag_h(A_b)   (128x128 per batch)
// grid (B), 256 threads
// ---------------------------------------------------------------------------
__global__ __launch_bounds__(256) void k5_M(
    const float* __restrict__ Awt, const float* __restrict__ proj_w,
    float* __restrict__ M)
{
  __shared__ float As[H][C][C];
  const int b = blockIdx.x, t = threadIdx.x;
  for (int e = t; e < H * C * C; e += 256)
    ((float*)As)[e] = Awt[(size_t)b * H * C * C + e];
  __syncthreads();
  for (int e = t; e < CD * CD; e += 256) {
    int o = e >> 7, cc = e & 127;
    int h = cc >> 5, j = cc & 31;
    float s = 0.f;
    const float* Pr = proj_w + o * CD + h * C;
#pragma unroll
    for (int i = 0; i < 32; i++) s += Pr[i] * As[h][i][j];
    M[(size_t)b * CD * CD + e] = s;
  }
}

// ---------------------------------------------------------------------------
// K6: out[b] = M_b @ V_b + proj_b   (128 x 4096, K=128)
// Same register-tiled GEMM as K1 minus halo/dw. grid (64, B), 128 threads.
// ---------------------------------------------------------------------------
__global__ __launch_bounds__(128) void k6_out(
    const float* __restrict__ qkvd, const float* __restrict__ M,
    const float* __restrict__ proj_b, float* __restrict__ out)
{
  __shared__ float Ms[16][132];
  __shared__ float vs[16][64];
  const int t = threadIdx.x;
  const int ytile = blockIdx.x, b = blockIdx.y;
  const int y0 = ytile * 64;
  const int to = t >> 3, ty = t & 7;
  const float* vb = qkvd + ((size_t)b * O3 + 2 * CD) * N;
  const float* Mb = M + (size_t)b * CD * CD;

  float acc[8][8];
#pragma unroll
  for (int i = 0; i < 8; i++)
#pragma unroll
    for (int y = 0; y < 8; y++) acc[i][y] = 0.f;

  for (int k0 = 0; k0 < CD; k0 += 16) {
#pragma unroll
    for (int r = 0; r < 4; r++) {
      int f = t + 128 * r;
      int o = f >> 2, kk0 = (f & 3) << 2;
      float4 w4 = *(const float4*)(Mb + (size_t)o * CD + k0 + kk0);
      Ms[kk0 + 0][o] = w4.x; Ms[kk0 + 1][o] = w4.y;
      Ms[kk0 + 2][o] = w4.z; Ms[kk0 + 3][o] = w4.w;
    }
#pragma unroll
    for (int r = 0; r < 8; r++) {
      int e = t + 128 * r;
      int kk = e >> 6, cy = e & 63;
      vs[kk][cy] = vb[(size_t)(k0 + kk) * N + y0 + cy];
    }
    __syncthreads();
#pragma unroll
    for (int kk = 0; kk < 16; kk++) {
      float4 a0 = *(const float4*)&Ms[kk][to * 8];
      float4 a1 = *(const float4*)&Ms[kk][to * 8 + 4];
      float4 b0 = *(const float4*)&vs[kk][ty * 8];
      float4 b1 = *(const float4*)&vs[kk][ty * 8 + 4];
      float at[8] = {a0.x, a0.y, a0.z, a0.w, a1.x, a1.y, a1.z, a1.w};
      float bt[8] = {b0.x, b0.y, b0.z, b0.w, b1.x, b1.y, b1.z, b1.w};
#pragma unroll
      for (int i = 0; i < 8; i++)
#pragma unroll
        for (int y = 0; y < 8; y++) acc[i][y] += at[i] * bt[y];
    }
    __syncthreads();
  }

#pragma unroll
  for (int i = 0; i < 8; i++) {
    int o = to * 8 + i;
    float pb = proj_b[o];
    float4 r0 = make_float4(acc[i][0] + pb, acc[i][1] + pb,
                            acc[i][2] + pb, acc[i][3] + pb);
    float4 r1 = make_float4(acc[i][4] + pb, acc[i][5] + pb,
                            acc[i][6] + pb, acc[i][7] + pb);
    float* dst = out + ((size_t)b * CD + o) * N + y0 + ty * 8;
    *(float4*)dst = r0;
    *(float4*)(dst + 4) = r1;
  }
}

extern "C" void kernel_launch(void* const* d_in, const int* in_sizes, int n_in,
                              void* d_out, int out_size, void* d_ws, size_t ws_size,
                              hipStream_t stream)
{
  (void)in_sizes; (void)n_in; (void)out_size; (void)ws_size;
  const float* x           = (const float*)d_in[0];
  const float* qkv_w       = (const float*)d_in[1];
  const float* qkv_b       = (const float*)d_in[2];
  const float* dw_w        = (const float*)d_in[3];
  const float* dw_b        = (const float*)d_in[4];
  const float* proj_w      = (const float*)d_in[5];
  const float* proj_b      = (const float*)d_in[6];
  const float* temperature = (const float*)d_in[7];
  const float* attn_w      = (const float*)d_in[8];
  float* out = (float*)d_out;

  float* ws      = (float*)d_ws;
  float* qkvd    = ws;                                  // B*O3*N      = 50,331,648 f
  float* attnraw = qkvd + (size_t)B * O3 * N;           // B*H*C*C     =    131,072 f
  float* sumsq   = attnraw + (size_t)B * H * C * C;     // B*256       =      8,192 f
  float* Awt     = sumsq + (size_t)B * 256;             // B*H*C*C     =    131,072 f
  float* M       = Awt + (size_t)B * H * C * C;         // B*CD*CD     =    524,288 f
  // total ~204.6 MB of workspace

  // zero the atomic accumulators (attnraw + sumsq are adjacent)
  hipMemsetAsync(attnraw, 0, (size_t)(B * H * C * C + B * 256) * sizeof(float),
                 stream);

  k1_qkv_dw<<<dim3(67, 3, 32), 128, 0, stream>>>(x, qkv_w, qkv_b, dw_w, dw_b, qkvd);
  k3_attn  <<<dim3(4, H, B),   256, 0, stream>>>(qkvd, attnraw, sumsq);
  k4_post  <<<dim3(H, B),       64, 0, stream>>>(attnraw, sumsq, temperature, attn_w, Awt);
  k5_M     <<<dim3(B),         256, 0, stream>>>(Awt, proj_w, M);
  k6_out   <<<dim3(64, B),     128, 0, stream>>>(qkvd, M, proj_b, out);
}

// Round 2
// 360.888 us; speedup vs baseline: 2.1964x; 2.1964x over previous
//
#include <hip/hip_runtime.h>

#define B_ 32
#define CD 128
#define O3 384
#define N  4096
#define H_ 4
#define C_ 32

typedef __bf16 bf16x8 __attribute__((ext_vector_type(8)));
typedef float floatx4 __attribute__((ext_vector_type(4)));

__device__ __forceinline__ float b2f(unsigned short u) {
  union { unsigned int i; float f; } v; v.i = ((unsigned int)u) << 16; return v.f;
}
// round-to-nearest-even fp32 -> bf16 (no NaN in this workload)
__device__ __forceinline__ unsigned short f2b(float f) {
  unsigned int bits = __builtin_bit_cast(unsigned int, f);
  unsigned int r = (bits + 0x7FFFu + ((bits >> 16) & 1u)) >> 16;
  return (unsigned short)r;
}

// ---------------------------------------------------------------------------
// K0a: transpose+convert x [b][c][n] fp32 -> xT [b][n][c] bf16.
// tile 32c x 64n via LDS. grid (64, 4, 32), 256 thr.
// ---------------------------------------------------------------------------
__global__ __launch_bounds__(256) void k0_xt(const float* __restrict__ x,
                                             unsigned short* __restrict__ xT)
{
  __shared__ float xt[32 * 68];
  const int t = threadIdx.x;
  const int n0 = blockIdx.x * 64, c0 = blockIdx.y * 32, b = blockIdx.z;
  const float* xb = x + ((size_t)b * CD + c0) * N + n0;
#pragma unroll
  for (int i = 0; i < 2; i++) {
    int f = i * 256 + t;
    int c = f >> 4, n4 = (f & 15) * 4;
    float4 v = *(const float4*)(xb + (size_t)c * N + n4);
    *(float4*)&xt[c * 68 + n4] = v;
  }
  __syncthreads();
  int n = t >> 2, cb = (t & 3) * 8;
  unsigned short tmp[8];
#pragma unroll
  for (int j = 0; j < 8; j++) tmp[j] = f2b(xt[(cb + j) * 68 + n]);
  *(uint4*)(xT + ((size_t)b * N + n0 + n) * CD + c0 + cb) = *(uint4*)tmp;
}

// K0b: qkv_w fp32 -> bf16 [o][k]. grid 48 x 256, 4 elems/thread.
__global__ void k0_w(const float* __restrict__ qkv_w,
                     unsigned short* __restrict__ qkv_wb)
{
  int e = (blockIdx.x * 256 + threadIdx.x) * 4;
  float4 v = *(const float4*)(qkv_w + e);
  unsigned short tmp[4] = {f2b(v.x), f2b(v.y), f2b(v.z), f2b(v.w)};
  *(uint2*)(qkv_wb + e) = *(uint2*)tmp;
}

// ---------------------------------------------------------------------------
// K1: MFMA GEMM (qkv_w[128o-tile x 128k] @ xT[64y x 128k]^T) + bias + 3-tap
// depthwise along y + bias. Outputs: q,k -> qkvd_qk[b][o2][n] bf16 (o2<256);
// v -> vT[b][n][c] bf16 (transposed in LDS for K6's B-operand).
// 256 thr = 4 waves; wave = 32o x 64y = 2x4 mfma 16x16x32 tiles, K=128.
// grid (67, 3, 32). LDS 52224 B -> 3 blocks/CU.
// ---------------------------------------------------------------------------
__global__ __launch_bounds__(256) void k1_qkv_dw(
    const unsigned short* __restrict__ xT, const unsigned short* __restrict__ qkv_wb,
    const float* __restrict__ qkv_b, const float* __restrict__ dw_w,
    const float* __restrict__ dw_b, unsigned short* __restrict__ qkvd_qk,
    unsigned short* __restrict__ vT)
{
  __shared__ __align__(16) char smem[52224];
  unsigned short* As = (unsigned short*)smem;             // [128][136]
  unsigned short* Bs = (unsigned short*)(smem + 34816);   // [64][136]
  float* pres = (float*)smem;                             // [128][66] (reuse)
  unsigned short* vres = (unsigned short*)(smem + 33792); // [62][136] (reuse)

  const int t = threadIdx.x;
  const int ytile = blockIdx.x, otile = blockIdx.y, b = blockIdx.z;
  const int obase = otile * 128;
  const int ybase = ytile * 62 - 1;
  const int wv = t >> 6, l = t & 63;
  const int quad = l >> 4, lm = l & 15;

#pragma unroll
  for (int i = 0; i < 8; i++) {                 // stage A (qkv_w tile)
    int f = i * 256 + t;
    int o = f >> 4, c8 = (f & 15) * 8;
    *(uint4*)&As[o * 136 + c8] =
        *(const uint4*)(qkv_wb + (size_t)(obase + o) * CD + c8);
  }
#pragma unroll
  for (int i = 0; i < 4; i++) {                 // stage B (xT rows, zero halo)
    int f = i * 256 + t;
    int row = f >> 4, c8 = (f & 15) * 8;
    int yg = ybase + row;
    uint4 v = make_uint4(0u, 0u, 0u, 0u);
    if (yg >= 0 && yg < N)
      v = *(const uint4*)(xT + ((size_t)b * N + yg) * CD + c8);
    *(uint4*)&Bs[row * 136 + c8] = v;
  }
  __syncthreads();

  floatx4 acc[2][4];
#pragma unroll
  for (int mt = 0; mt < 2; mt++)
#pragma unroll
    for (int nt = 0; nt < 4; nt++) acc[mt][nt] = (floatx4){0.f, 0.f, 0.f, 0.f};

#pragma unroll
  for (int ks = 0; ks < 4; ks++) {
    int k0 = ks * 32 + quad * 8;
    bf16x8 a0 = *(const bf16x8*)&As[(wv * 32 + lm) * 136 + k0];
    bf16x8 a1 = *(const bf16x8*)&As[(wv * 32 + 16 + lm) * 136 + k0];
#pragma unroll
    for (int nt = 0; nt < 4; nt++) {
      bf16x8 bb = *(const bf16x8*)&Bs[(nt * 16 + lm) * 136 + k0];
      acc[0][nt] = __builtin_amdgcn_mfma_f32_16x16x32_bf16(a0, bb, acc[0][nt], 0, 0, 0);
      acc[1][nt] = __builtin_amdgcn_mfma_f32_16x16x32_bf16(a1, bb, acc[1][nt], 0, 0, 0);
    }
  }
  __syncthreads();   // done reading As/Bs; reuse LDS as pres

  // acc -> pres (+qkv bias; zero outside [0,N) = conv zero-padding)
#pragma unroll
  for (int mt = 0; mt < 2; mt++)
#pragma unroll
    for (int r = 0; r < 4; r++) {
      int o = wv * 32 + mt * 16 + quad * 4 + r;
      float bias = qkv_b[obase + o];
#pragma unroll
      for (int nt = 0; nt < 4; nt++) {
        int y = nt * 16 + lm;
        int yg = ybase + y;
        pres[o * 66 + y] = (yg >= 0 && yg < N) ? (acc[mt][nt][r] + bias) : 0.f;
      }
    }
  __syncthreads();

  // depthwise 3-tap + bias
  const int y2 = t & 63, og = t >> 6;
  if (y2 >= 1 && y2 <= 62) {
    int yo = ybase + y2;
    if (yo < N) {
      if (otile < 2) {
        for (int r = 0; r < 32; r++) {
          int o = og * 32 + r;
          int oo = obase + o;
          float v = dw_w[oo * 9 + 1] * pres[o * 66 + y2 - 1] +
                    dw_w[oo * 9 + 4] * pres[o * 66 + y2] +
                    dw_w[oo * 9 + 7] * pres[o * 66 + y2 + 1] + dw_b[oo];
          qkvd_qk[((size_t)b * 256 + obase + o) * N + yo] = f2b(v);
        }
      } else {
        for (int r = 0; r < 32; r++) {
          int o = og * 32 + r;
          int oo = obase + o;
          float v = dw_w[oo * 9 + 1] * pres[o * 66 + y2 - 1] +
                    dw_w[oo * 9 + 4] * pres[o * 66 + y2] +
                    dw_w[oo * 9 + 7] * pres[o * 66 + y2 + 1] + dw_b[oo];
          vres[(y2 - 1) * 136 + o] = f2b(v);   // transposed staging for vT
        }
      }
    }
  }
  if (otile == 2) {
    __syncthreads();
#pragma unroll
    for (int i = 0; i < 4; i++) {
      int f = i * 256 + t;
      if (f < 992) {
        int yr = f >> 4, cb = (f & 15) * 8;
        int yo = ybase + 1 + yr;
        if (yo < N)
          *(uint4*)(vT + ((size_t)b * N + yo) * CD + cb) =
              *(uint4*)&vres[yr * 136 + cb];
      }
    }
  }
}

// ---------------------------------------------------------------------------
// K3: QK^T Gram (32x32 per b,h) + sum-of-squares, bf16 inputs / fp32 accum.
// grid (4, H, B), 256 thr; lane owns 4x4 (i,j), 8-y vector steps.
// ---------------------------------------------------------------------------
__global__ __launch_bounds__(256) void k3_attn(
    const unsigned short* __restrict__ qkvd_qk, float* __restrict__ attnraw,
    float* __restrict__ sumsq)
{
  const int ytile = blockIdx.x, h = blockIdx.y, b = blockIdx.z;
  const int t = threadIdx.x;
  const int g = t >> 6, l = t & 63;
  const int i0 = ((l >> 3) & 7) * 4;
  const int j0 = (l & 7) * 4;
  const unsigned short* qb = qkvd_qk + ((size_t)b * 256 + h * C_) * N;
  const unsigned short* kb = qkvd_qk + ((size_t)b * 256 + 128 + h * C_) * N;
  const int y0 = ytile * 1024 + g * 256;

  float acc[4][4];
#pragma unroll
  for (int ii = 0; ii < 4; ii++)
#pragma unroll
    for (int jj = 0; jj < 4; jj++) acc[ii][jj] = 0.f;
  float sq[4] = {0.f, 0.f, 0.f, 0.f};
  float sk[4] = {0.f, 0.f, 0.f, 0.f};

  for (int y = y0; y < y0 + 256; y += 8) {
    float qf[4][8], kf[4][8];
#pragma unroll
    for (int ii = 0; ii < 4; ii++) {
      uint4 u = *(const uint4*)(qb + (size_t)(i0 + ii) * N + y);
      const unsigned short* p = (const unsigned short*)&u;
#pragma unroll
      for (int j = 0; j < 8; j++) qf[ii][j] = b2f(p[j]);
    }
#pragma unroll
    for (int jj = 0; jj < 4; jj++) {
      uint4 u = *(const uint4*)(kb + (size_t)(j0 + jj) * N + y);
      const unsigned short* p = (const unsigned short*)&u;
#pragma unroll
      for (int j = 0; j < 8; j++) kf[jj][j] = b2f(p[j]);
    }
#pragma unroll
    for (int ii = 0; ii < 4; ii++)
#pragma unroll
      for (int jj = 0; jj < 4; jj++) {
        float s = 0.f;
#pragma unroll
        for (int j = 0; j < 8; j++) s += qf[ii][j] * kf[jj][j];
        acc[ii][jj] += s;
      }
    if (j0 == 0)
#pragma unroll
      for (int ii = 0; ii < 4; ii++) {
        float s = 0.f;
#pragma unroll
        for (int j = 0; j < 8; j++) s += qf[ii][j] * qf[ii][j];
        sq[ii] += s;
      }
    if (i0 == 0)
#pragma unroll
      for (int jj = 0; jj < 4; jj++) {
        float s = 0.f;
#pragma unroll
        for (int j = 0; j < 8; j++) s += kf[jj][j] * kf[jj][j];
        sk[jj] += s;
      }
  }

#pragma unroll
  for (int ii = 0; ii < 4; ii++)
#pragma unroll
    for (int jj = 0; jj < 4; jj++)
      atomicAdd(&attnraw[(((size_t)b * H_ + h) * C_ + i0 + ii) * C_ + j0 + jj],
                acc[ii][jj]);
  if (j0 == 0)
#pragma unroll
    for (int ii = 0; ii < 4; ii++)
      atomicAdd(&sumsq[b * 256 + h * C_ + i0 + ii], sq[ii]);
  if (i0 == 0)
#pragma unroll
    for (int jj = 0; jj < 4; jj++)
      atomicAdd(&sumsq[b * 256 + CD + h * C_ + j0 + jj], sk[jj]);
}

// ---------------------------------------------------------------------------
// K4: normalize, temperature, exact stable top-k ranks, fold 4 masked
// softmaxes into one combined weight matrix Awt. grid (H, B), 64 thr.
// ---------------------------------------------------------------------------
__global__ void k4_post(
    const float* __restrict__ attnraw, const float* __restrict__ sumsq,
    const float* __restrict__ temperature, const float* __restrict__ attn_w,
    float* __restrict__ Awt)
{
  __shared__ float La[32][33];
  __shared__ float Le[32][33];
  __shared__ int   Lr[32][32];
  __shared__ float rq[32], rk[32];
  const int h = blockIdx.x, b = blockIdx.y, t = threadIdx.x;

  if (t < 32)
    rq[t] = 1.f / fmaxf(sqrtf(sumsq[b * 256 + h * C_ + t]), 1e-12f);
  else if (t < 64)
    rk[t - 32] = 1.f / fmaxf(sqrtf(sumsq[b * 256 + CD + h * C_ + (t - 32)]), 1e-12f);
  __syncthreads();

  const float temp = temperature[h];
  const float* ar = attnraw + ((size_t)b * H_ + h) * C_ * C_;
  for (int e = t; e < C_ * C_; e += 64) {
    int i = e >> 5, j = e & 31;
    La[i][j] = ar[e] * rq[i] * rk[j] * temp;
  }
  __syncthreads();

  if (t < 32) {
    const int i = t;
    float m = -1e30f;
    for (int j = 0; j < 32; j++) m = fmaxf(m, La[i][j]);
    float S0 = 0.f, S1 = 0.f, S2 = 0.f, S3 = 0.f;
    for (int j = 0; j < 32; j++) {
      float v = La[i][j];
      int r = 0;
      for (int j2 = 0; j2 < 32; j2++) {
        float v2 = La[i][j2];
        r += (v2 > v) || (v2 == v && j2 < j);
      }
      float e = expf(v - m);
      Le[i][j] = e;
      Lr[i][j] = r;
      if (r < 16) S0 += e;
      if (r < 21) S1 += e;
      if (r < 24) S2 += e;
      if (r < 25) S3 += e;
    }
    float w0 = attn_w[0] / S0, w1 = attn_w[1] / S1;
    float w2 = attn_w[2] / S2, w3 = attn_w[3] / S3;
    for (int j = 0; j < 32; j++) {
      int r = Lr[i][j];
      float cmb = (r < 16 ? w0 : 0.f) + (r < 21 ? w1 : 0.f) +
                  (r < 24 ? w2 : 0.f) + (r < 25 ? w3 : 0.f);
      Awt[(((size_t)b * H_ + h) * C_ + i) * C_ + j] = Le[i][j] * cmb;
    }
  }
}

// ---------------------------------------------------------------------------
// K5: Mb = bf16( proj_w @ blockdiag_h(A_b) )  (128x128 per batch, [o][c])
// ---------------------------------------------------------------------------
__global__ __launch_bounds__(256) void k5_M(
    const float* __restrict__ Awt, const float* __restrict__ proj_w,
    unsigned short* __restrict__ Mb)
{
  __shared__ float Asm[H_][C_][C_];
  const int b = blockIdx.x, t = threadIdx.x;
  for (int e = t; e < H_ * C_ * C_; e += 256)
    ((float*)Asm)[e] = Awt[(size_t)b * H_ * C_ * C_ + e];
  __syncthreads();
  for (int e = t; e < CD * CD; e += 256) {
    int o = e >> 7, cc = e & 127;
    int h = cc >> 5, j = cc & 31;
    float s = 0.f;
    const float* Pr = proj_w + o * CD + h * C_;
#pragma unroll
    for (int i = 0; i < 32; i++) s += Pr[i] * Asm[h][i][j];
    Mb[(size_t)b * CD * CD + e] = f2b(s);
  }
}

// ---------------------------------------------------------------------------
// K6: out[b] = Mb @ V_b^T + proj_b via MFMA. A=Mb[128o][128k], B=vT[y][128k].
// Block: 128o x 128y, 4 waves, wave = 32o x 128y. grid (32, 32).
// ---------------------------------------------------------------------------
__global__ __launch_bounds__(256) void k6_out(
    const unsigned short* __restrict__ vT, const unsigned short* __restrict__ Mb,
    const float* __restrict__ proj_b, float* __restrict__ out)
{
  __shared__ unsigned short As[128 * 136];
  __shared__ unsigned short Bs[128 * 136];
  const int t = threadIdx.x;
  const int y0 = blockIdx.x * 128, b = blockIdx.y;
  const int wv = t >> 6, l = t & 63, quad = l >> 4, lm = l & 15;

#pragma unroll
  for (int i = 0; i < 8; i++) {
    int f = i * 256 + t;
    int o = f >> 4, c8 = (f & 15) * 8;
    *(uint4*)&As[o * 136 + c8] =
        *(const uint4*)(Mb + ((size_t)b * CD + o) * CD + c8);
  }
#pragma unroll
  for (int i = 0; i < 8; i++) {
    int f = i * 256 + t;
    int row = f >> 4, c8 = (f & 15) * 8;
    *(uint4*)&Bs[row * 136 + c8] =
        *(const uint4*)(vT + ((size_t)b * N + y0 + row) * CD + c8);
  }
  __syncthreads();

  floatx4 acc[2][8];
#pragma unroll
  for (int mt = 0; mt < 2; mt++)
#pragma unroll
    for (int nt = 0; nt < 8; nt++) acc[mt][nt] = (floatx4){0.f, 0.f, 0.f, 0.f};

#pragma unroll
  for (int ks = 0; ks < 4; ks++) {
    int k0 = ks * 32 + quad * 8;
    bf16x8 a0 = *(const bf16x8*)&As[(wv * 32 + lm) * 136 + k0];
    bf16x8 a1 = *(const bf16x8*)&As[(wv * 32 + 16 + lm) * 136 + k0];
#pragma unroll
    for (int nt = 0; nt < 8; nt++) {
      bf16x8 bb = *(const bf16x8*)&Bs[(nt * 16 + lm) * 136 + k0];
      acc[0][nt] = __builtin_amdgcn_mfma_f32_16x16x32_bf16(a0, bb, acc[0][nt], 0, 0, 0);
      acc[1][nt] = __builtin_amdgcn_mfma_f32_16x16x32_bf16(a1, bb, acc[1][nt], 0, 0, 0);
    }
  }

#pragma unroll
  for (int mt = 0; mt < 2; mt++)
#pragma unroll
    for (int r = 0; r < 4; r++) {
      int o = wv * 32 + mt * 16 + quad * 4 + r;
      float pb = proj_b[o];
#pragma unroll
      for (int nt = 0; nt < 8; nt++) {
        int y = y0 + nt * 16 + lm;
        out[((size_t)b * CD + o) * N + y] = acc[mt][nt][r] + pb;
      }
    }
}

extern "C" void kernel_launch(void* const* d_in, const int* in_sizes, int n_in,
                              void* d_out, int out_size, void* d_ws, size_t ws_size,
                              hipStream_t stream)
{
  (void)in_sizes; (void)n_in; (void)out_size; (void)ws_size;
  const float* x           = (const float*)d_in[0];
  const float* qkv_w       = (const float*)d_in[1];
  const float* qkv_b       = (const float*)d_in[2];
  const float* dw_w        = (const float*)d_in[3];
  const float* dw_b        = (const float*)d_in[4];
  const float* proj_w      = (const float*)d_in[5];
  const float* proj_b      = (const float*)d_in[6];
  const float* temperature = (const float*)d_in[7];
  const float* attn_w      = (const float*)d_in[8];
  float* out = (float*)d_out;

  unsigned short* xT       = (unsigned short*)d_ws;        // 16,777,216
  unsigned short* qkv_wb   = xT + (size_t)16777216;        //     49,152
  unsigned short* qkvd_qk  = qkv_wb + (size_t)49152;       // 33,554,432
  unsigned short* vT       = qkvd_qk + (size_t)33554432;   // 16,777,216
  float* attnraw = (float*)(vT + (size_t)16777216);        //    131,072 f
  float* sumsq   = attnraw + 131072;                       //      8,192 f
  float* Awt     = sumsq + 8192;                           //    131,072 f
  unsigned short* Mb = (unsigned short*)(Awt + 131072);    //    524,288
  // total ~136.4 MB workspace

  hipMemsetAsync(attnraw, 0, (size_t)(131072 + 8192) * sizeof(float), stream);

  k0_xt    <<<dim3(64, 4, 32), 256, 0, stream>>>(x, xT);
  k0_w     <<<dim3(48),        256, 0, stream>>>(qkv_w, qkv_wb);
  k1_qkv_dw<<<dim3(67, 3, 32), 256, 0, stream>>>(xT, qkv_wb, qkv_b, dw_w, dw_b,
                                                 qkvd_qk, vT);
  k3_attn  <<<dim3(4, H_, B_), 256, 0, stream>>>(qkvd_qk, attnraw, sumsq);
  k4_post  <<<dim3(H_, B_),     64, 0, stream>>>(attnraw, sumsq, temperature,
                                                 attn_w, Awt);
  k5_M     <<<dim3(B_),        256, 0, stream>>>(Awt, proj_w, Mb);
  k6_out   <<<dim3(32, B_),    256, 0, stream>>>(vT, Mb, proj_b, out);
}

// Round 3
// 291.828 us; speedup vs baseline: 2.7162x; 1.2366x over previous
//
#include <hip/hip_runtime.h>

#define B_ 32
#define CD 128
#define O3 384
#define N  4096
#define H_ 4
#define C_ 32

typedef __bf16 bf16x8 __attribute__((ext_vector_type(8)));
typedef float floatx4 __attribute__((ext_vector_type(4)));

#define MFMA16(a, b, c) __builtin_amdgcn_mfma_f32_16x16x32_bf16(a, b, c, 0, 0, 0)

__device__ __forceinline__ unsigned short f2b(float f) {
  unsigned int bits = __builtin_bit_cast(unsigned int, f);
  unsigned int r = (bits + 0x7FFFu + ((bits >> 16) & 1u)) >> 16;
  return (unsigned short)r;
}

// ---------------------------------------------------------------------------
// K0a: transpose+convert x [b][c][n] fp32 -> xT [b][n][c] bf16.
// ---------------------------------------------------------------------------
__global__ __launch_bounds__(256) void k0_xt(const float* __restrict__ x,
                                             unsigned short* __restrict__ xT)
{
  __shared__ float xt[32 * 68];
  const int t = threadIdx.x;
  const int n0 = blockIdx.x * 64, c0 = blockIdx.y * 32, b = blockIdx.z;
  const float* xb = x + ((size_t)b * CD + c0) * N + n0;
#pragma unroll
  for (int i = 0; i < 2; i++) {
    int f = i * 256 + t;
    int c = f >> 4, n4 = (f & 15) * 4;
    float4 v = *(const float4*)(xb + (size_t)c * N + n4);
    *(float4*)&xt[c * 68 + n4] = v;
  }
  __syncthreads();
  int n = t >> 2, cb = (t & 3) * 8;
  unsigned short tmp[8];
#pragma unroll
  for (int j = 0; j < 8; j++) tmp[j] = f2b(xt[(cb + j) * 68 + n]);
  *(uint4*)(xT + ((size_t)b * N + n0 + n) * CD + c0 + cb) = *(uint4*)tmp;
}

// K0b: qkv_w and proj_w fp32 -> bf16. grid 64 x 256, 4 elems/thread.
__global__ void k0_w(const float* __restrict__ qkv_w,
                     const float* __restrict__ proj_w,
                     unsigned short* __restrict__ qkv_wb,
                     unsigned short* __restrict__ proj_wb)
{
  int e = (blockIdx.x * 256 + threadIdx.x) * 4;
  const float* src; unsigned short* dst; int off;
  if (e < 49152) { src = qkv_w; dst = qkv_wb; off = e; }
  else           { src = proj_w; dst = proj_wb; off = e - 49152; }
  float4 v = *(const float4*)(src + off);
  unsigned short tmp[4] = {f2b(v.x), f2b(v.y), f2b(v.z), f2b(v.w)};
  *(uint2*)(dst + off) = *(uint2*)tmp;
}

// ---------------------------------------------------------------------------
// K1: MFMA GEMM (128o x 128y tile, K=128) + bias + 3-tap depthwise + bias.
// q,k (otile<2) -> qkvd[b][o2][n] bf16; v (otile==2) -> vT[b][n][c] bf16
// via [y][o]-layout LDS + sliding-window dw with per-thread register taps.
// grid (33, 3, 32), 256 thr, LDS 69632 -> 2 blocks/CU.
// ---------------------------------------------------------------------------
__global__ __launch_bounds__(256) void k1_qkv_dw(
    const unsigned short* __restrict__ xT, const unsigned short* __restrict__ qkv_wb,
    const float* __restrict__ qkv_b, const float* __restrict__ dw_w,
    const float* __restrict__ dw_b, unsigned short* __restrict__ qkvd,
    unsigned short* __restrict__ vT)
{
  __shared__ __align__(16) char smem[69632];
  unsigned short* As = (unsigned short*)smem;            // [128][136]
  unsigned short* Bs = (unsigned short*)(smem + 34816);  // [128][136]
  float* pres = (float*)smem;                            // reuse after mfma

  const int t = threadIdx.x;
  const int ytile = blockIdx.x, otile = blockIdx.y, b = blockIdx.z;
  const int obase = otile * 128;
  const int ybase = ytile * 126 - 1;
  const int wv = t >> 6, l = t & 63, quad = l >> 4, lm = l & 15;

#pragma unroll
  for (int i = 0; i < 8; i++) {                 // stage A (weights)
    int f = i * 256 + t;
    int o = f >> 4, c8 = (f & 15) * 8;
    *(uint4*)&As[o * 136 + c8] =
        *(const uint4*)(qkv_wb + (size_t)(obase + o) * CD + c8);
  }
#pragma unroll
  for (int i = 0; i < 8; i++) {                 // stage B (xT rows, zero halo)
    int f = i * 256 + t;
    int row = f >> 4, c8 = (f & 15) * 8;
    int yg = ybase + row;
    uint4 v = make_uint4(0u, 0u, 0u, 0u);
    if (yg >= 0 && yg < N)
      v = *(const uint4*)(xT + ((size_t)b * N + yg) * CD + c8);
    *(uint4*)&Bs[row * 136 + c8] = v;
  }
  __syncthreads();

  floatx4 acc[2][8];
#pragma unroll
  for (int mt = 0; mt < 2; mt++)
#pragma unroll
    for (int nt = 0; nt < 8; nt++) acc[mt][nt] = (floatx4){0.f, 0.f, 0.f, 0.f};

#pragma unroll
  for (int ks = 0; ks < 4; ks++) {
    int k0 = ks * 32 + quad * 8;
    bf16x8 a0 = *(const bf16x8*)&As[(wv * 32 + lm) * 136 + k0];
    bf16x8 a1 = *(const bf16x8*)&As[(wv * 32 + 16 + lm) * 136 + k0];
#pragma unroll
    for (int nt = 0; nt < 8; nt++) {
      bf16x8 bb = *(const bf16x8*)&Bs[(nt * 16 + lm) * 136 + k0];
      acc[0][nt] = MFMA16(a0, bb, acc[0][nt]);
      acc[1][nt] = MFMA16(a1, bb, acc[1][nt]);
    }
  }
  __syncthreads();   // As/Bs dead; reuse as pres

  if (otile < 2) {
    // pres[o][y], stride 130 (write banks 2-way)
#pragma unroll
    for (int mt = 0; mt < 2; mt++)
#pragma unroll
      for (int r = 0; r < 4; r++) {
        int o = wv * 32 + mt * 16 + quad * 4 + r;
        float bias = qkv_b[obase + o];
#pragma unroll
        for (int nt = 0; nt < 8; nt++) {
          int y = nt * 16 + lm;
          int yg = ybase + y;
          pres[o * 130 + y] = (yg >= 0 && yg < N) ? (acc[mt][nt][r] + bias) : 0.f;
        }
      }
    __syncthreads();
    const int y2 = t & 127, og = t >> 7;     // wave-uniform o-group
    int yo = ybase + y2;
    bool ok = (y2 >= 1) && (y2 <= 126) && (yo < N);
    for (int r = 0; r < 64; r++) {
      int o = og * 64 + r;
      int oo = obase + o;
      float v = dw_w[oo * 9 + 1] * pres[o * 130 + y2 - 1] +
                dw_w[oo * 9 + 4] * pres[o * 130 + y2] +
                dw_w[oo * 9 + 7] * pres[o * 130 + y2 + 1] + dw_b[oo];
      if (ok) qkvd[((size_t)b * 256 + oo) * N + yo] = f2b(v);
    }
  } else {
    // vpre[y][o], stride 131; taps in registers, sliding window along y
#pragma unroll
    for (int mt = 0; mt < 2; mt++)
#pragma unroll
      for (int r = 0; r < 4; r++) {
        int o = wv * 32 + mt * 16 + quad * 4 + r;
        float bias = qkv_b[obase + o];
#pragma unroll
        for (int nt = 0; nt < 8; nt++) {
          int y = nt * 16 + lm;
          int yg = ybase + y;
          pres[y * 131 + o] = (yg >= 0 && yg < N) ? (acc[mt][nt][r] + bias) : 0.f;
        }
      }
    __syncthreads();
    const int o = t & 127, half = t >> 7;
    const int oo = obase + o;
    const float w0 = dw_w[oo * 9 + 1], w1 = dw_w[oo * 9 + 4],
                w2 = dw_w[oo * 9 + 7], wb = dw_b[oo];
    int ys = 1 + half * 63;                  // halves: y 1..63, 64..126
    float pm = pres[(ys - 1) * 131 + o];
    float pc = pres[ys * 131 + o];
    for (int yy = ys; yy < ys + 63; yy++) {
      float pp = pres[(yy + 1) * 131 + o];
      int yo2 = ybase + yy;
      if (yo2 < N) {
        float v = w0 * pm + w1 * pc + w2 * pp + wb;
        vT[((size_t)b * N + yo2) * CD + o] = f2b(v);
      }
      pm = pc; pc = pp;
    }
  }
}

// ---------------------------------------------------------------------------
// K3: MFMA Gram. Per (ns,h,b): 32x32 QK^T partial over 1024 n, plus Q/K
// row-norms via self-MFMA diagonals (A and B fragment lane maps coincide).
// Writes non-atomic partials part[b][h][ns][2048]: QK 0..1023, qd 1024..1055,
// kd 1056..1087. grid (4, H, B), 256 thr.
// ---------------------------------------------------------------------------
__global__ __launch_bounds__(256) void k3_gram(
    const unsigned short* __restrict__ qkvd, float* __restrict__ part)
{
  __shared__ unsigned short Qs[32 * 136];
  __shared__ unsigned short Ks[32 * 136];
  __shared__ float red[4 * 8 * 272];   // [wv][tile][row*17+col]
  const int ns = blockIdx.x, h = blockIdx.y, b = blockIdx.z;
  const int t = threadIdx.x;
  const int wv = t >> 6, l = t & 63, quad = l >> 4, lm = l & 15;
  const unsigned short* qb = qkvd + ((size_t)b * 256 + h * C_) * N;
  const unsigned short* kb = qkvd + ((size_t)b * 256 + 128 + h * C_) * N;
  const int n0 = ns * 1024;

  floatx4 acc[8];
#pragma unroll
  for (int i = 0; i < 8; i++) acc[i] = (floatx4){0.f, 0.f, 0.f, 0.f};

  for (int ch = 0; ch < 8; ch++) {
    int nc = n0 + ch * 128;
#pragma unroll
    for (int i = 0; i < 4; i++) {            // stage 64 rows x 128 n
      int f = i * 256 + t;
      int row = f >> 4, n8 = (f & 15) * 8;
      const unsigned short* src = (row < 32) ? (qb + (size_t)row * N)
                                             : (kb + (size_t)(row - 32) * N);
      uint4 u = *(const uint4*)(src + nc + n8);
      unsigned short* dst = (row < 32) ? &Qs[row * 136 + n8]
                                       : &Ks[(row - 32) * 136 + n8];
      *(uint4*)dst = u;
    }
    __syncthreads();
    int k0 = wv * 32 + quad * 8;             // wave's 32-n window
    bf16x8 a0 = *(const bf16x8*)&Qs[lm * 136 + k0];
    bf16x8 a1 = *(const bf16x8*)&Qs[(16 + lm) * 136 + k0];
    bf16x8 b0 = *(const bf16x8*)&Ks[lm * 136 + k0];
    bf16x8 b1 = *(const bf16x8*)&Ks[(16 + lm) * 136 + k0];
    acc[0] = MFMA16(a0, b0, acc[0]);
    acc[1] = MFMA16(a0, b1, acc[1]);
    acc[2] = MFMA16(a1, b0, acc[2]);
    acc[3] = MFMA16(a1, b1, acc[3]);
    acc[4] = MFMA16(a0, a0, acc[4]);         // QQ (0,0) -> diag = ||q||^2
    acc[5] = MFMA16(a1, a1, acc[5]);
    acc[6] = MFMA16(b0, b0, acc[6]);
    acc[7] = MFMA16(b1, b1, acc[7]);
    __syncthreads();
  }

#pragma unroll
  for (int tl = 0; tl < 8; tl++)
#pragma unroll
    for (int r = 0; r < 4; r++)
      red[wv * 2176 + tl * 272 + (quad * 4 + r) * 17 + lm] = acc[tl][r];
  __syncthreads();

  float* pb = part + ((size_t)(b * H_ + h) * 4 + ns) * 2048;
  for (int e = t; e < 2048; e += 256) {
    int tl = e >> 8, rc = e & 255, row = rc >> 4, col = rc & 15;
    int a = tl * 272 + row * 17 + col;
    float s = red[a] + red[2176 + a] + red[2 * 2176 + a] + red[3 * 2176 + a];
    if (tl < 4) {
      int mt = tl >> 1, nt = tl & 1;
      pb[(mt * 16 + row) * 32 + nt * 16 + col] = s;
    } else if (row == col) {
      if (tl < 6) pb[1024 + (tl - 4) * 16 + row] = s;
      else        pb[1056 + (tl - 6) * 16 + row] = s;
    }
  }
}

// ---------------------------------------------------------------------------
// K45: per batch: sum ns-partials, normalize + temperature, exact stable
// top-k ranks, fold 4 masked softmaxes -> AwtT (bf16, transposed), then
// Mb = bf16(proj_w @ blockdiag(A)) via MFMA (wave per head). grid (B), 256.
// ---------------------------------------------------------------------------
__global__ __launch_bounds__(256) void k45(
    const float* __restrict__ part, const unsigned short* __restrict__ proj_wb,
    const float* __restrict__ temperature, const float* __restrict__ attn_w,
    unsigned short* __restrict__ Mb)
{
  __shared__ float La[H_][C_][33];
  __shared__ float sq2[256];
  __shared__ float rn[256];
  __shared__ float exL[H_][C_][33];
  __shared__ unsigned char rkL[H_][C_][C_];
  __shared__ unsigned short AwtT[H_][C_][40];
  const int b = blockIdx.x, t = threadIdx.x;

  // phase 0: sum 4 ns partials
  const float* pbb = part + (size_t)b * 32768;
  for (int e = t; e < 4 * 2048; e += 256) {
    int h = e >> 11, idx = e & 2047;
    if (idx < 1088) {
      const float* p = pbb + h * 8192 + idx;
      float s = p[0] + p[2048] + p[2 * 2048] + p[3 * 2048];
      if (idx < 1024) La[h][idx >> 5][idx & 31] = s;
      else if (idx < 1056) sq2[h * 32 + (idx - 1024)] = s;
      else sq2[128 + h * 32 + (idx - 1056)] = s;
    }
  }
  __syncthreads();
  rn[t] = 1.f / fmaxf(sqrtf(sq2[t]), 1e-12f);
  __syncthreads();
  for (int e = t; e < 4096; e += 256) {
    int h = e >> 10, i = (e >> 5) & 31, j = e & 31;
    La[h][i][j] *= rn[h * 32 + i] * rn[128 + h * 32 + j] * temperature[h];
  }
  __syncthreads();

  // phase 1: ranks + folded softmax
  if (t < 128) {
    int h = t >> 5, i = t & 31;
    float m = -1e30f;
    for (int j = 0; j < 32; j++) m = fmaxf(m, La[h][i][j]);
    float S0 = 0.f, S1 = 0.f, S2 = 0.f, S3 = 0.f;
    for (int j = 0; j < 32; j++) {
      float vj = La[h][i][j];
      int r = 0;
      for (int j2 = 0; j2 < 32; j2++) {
        float v2 = La[h][i][j2];
        r += (v2 > vj) || (v2 == vj && j2 < j);
      }
      float e = __expf(vj - m);
      exL[h][i][j] = e;
      rkL[h][i][j] = (unsigned char)r;
      if (r < 16) S0 += e;
      if (r < 21) S1 += e;
      if (r < 24) S2 += e;
      if (r < 25) S3 += e;
    }
    float w0 = attn_w[0] / S0, w1 = attn_w[1] / S1;
    float w2 = attn_w[2] / S2, w3 = attn_w[3] / S3;
    for (int j = 0; j < 32; j++) {
      int r = rkL[h][i][j];
      float cmb = (r < 16 ? w0 : 0.f) + (r < 21 ? w1 : 0.f) +
                  (r < 24 ? w2 : 0.f) + (r < 25 ? w3 : 0.f);
      AwtT[h][j][i] = f2b(exL[h][i][j] * cmb);   // transposed: [j][i]
    }
  }
  __syncthreads();

  // phase 2: M = proj_w @ blockdiag(A), wave per head, K=32 single-shot
  {
    const int wv = t >> 6, l = t & 63, quad = l >> 4, lm = l & 15;
    const int h = wv;
    bf16x8 bfr[2];
#pragma unroll
    for (int jt = 0; jt < 2; jt++)
      bfr[jt] = *(const bf16x8*)&AwtT[h][jt * 16 + lm][quad * 8];
#pragma unroll
    for (int mt = 0; mt < 8; mt++) {
      bf16x8 a = *(const bf16x8*)(proj_wb +
                    (size_t)(mt * 16 + lm) * CD + h * C_ + quad * 8);
#pragma unroll
      for (int jt = 0; jt < 2; jt++) {
        floatx4 acc = (floatx4){0.f, 0.f, 0.f, 0.f};
        acc = MFMA16(a, bfr[jt], acc);
#pragma unroll
        for (int r = 0; r < 4; r++) {
          int row = quad * 4 + r;
          Mb[(size_t)b * 16384 + (mt * 16 + row) * CD + h * C_ + jt * 16 + lm] =
              f2b(acc[r]);
        }
      }
    }
  }
}

// ---------------------------------------------------------------------------
// K6: out[b] = Mb @ V^T + proj_b via MFMA. grid (32, 32), 256 thr.
// ---------------------------------------------------------------------------
__global__ __launch_bounds__(256) void k6_out(
    const unsigned short* __restrict__ vT, const unsigned short* __restrict__ Mb,
    const float* __restrict__ proj_b, float* __restrict__ out)
{
  __shared__ unsigned short As[128 * 136];
  __shared__ unsigned short Bs[128 * 136];
  const int t = threadIdx.x;
  const int y0 = blockIdx.x * 128, b = blockIdx.y;
  const int wv = t >> 6, l = t & 63, quad = l >> 4, lm = l & 15;

#pragma unroll
  for (int i = 0; i < 8; i++) {
    int f = i * 256 + t;
    int o = f >> 4, c8 = (f & 15) * 8;
    *(uint4*)&As[o * 136 + c8] =
        *(const uint4*)(Mb + ((size_t)b * CD + o) * CD + c8);
  }
#pragma unroll
  for (int i = 0; i < 8; i++) {
    int f = i * 256 + t;
    int row = f >> 4, c8 = (f & 15) * 8;
    *(uint4*)&Bs[row * 136 + c8] =
        *(const uint4*)(vT + ((size_t)b * N + y0 + row) * CD + c8);
  }
  __syncthreads();

  floatx4 acc[2][8];
#pragma unroll
  for (int mt = 0; mt < 2; mt++)
#pragma unroll
    for (int nt = 0; nt < 8; nt++) acc[mt][nt] = (floatx4){0.f, 0.f, 0.f, 0.f};

#pragma unroll
  for (int ks = 0; ks < 4; ks++) {
    int k0 = ks * 32 + quad * 8;
    bf16x8 a0 = *(const bf16x8*)&As[(wv * 32 + lm) * 136 + k0];
    bf16x8 a1 = *(const bf16x8*)&As[(wv * 32 + 16 + lm) * 136 + k0];
#pragma unroll
    for (int nt = 0; nt < 8; nt++) {
      bf16x8 bb = *(const bf16x8*)&Bs[(nt * 16 + lm) * 136 + k0];
      acc[0][nt] = MFMA16(a0, bb, acc[0][nt]);
      acc[1][nt] = MFMA16(a1, bb, acc[1][nt]);
    }
  }

#pragma unroll
  for (int mt = 0; mt < 2; mt++)
#pragma unroll
    for (int r = 0; r < 4; r++) {
      int o = wv * 32 + mt * 16 + quad * 4 + r;
      float pb = proj_b[o];
#pragma unroll
      for (int nt = 0; nt < 8; nt++) {
        int y = y0 + nt * 16 + lm;
        out[((size_t)b * CD + o) * N + y] = acc[mt][nt][r] + pb;
      }
    }
}

extern "C" void kernel_launch(void* const* d_in, const int* in_sizes, int n_in,
                              void* d_out, int out_size, void* d_ws, size_t ws_size,
                              hipStream_t stream)
{
  (void)in_sizes; (void)n_in; (void)out_size; (void)ws_size;
  const float* x           = (const float*)d_in[0];
  const float* qkv_w       = (const float*)d_in[1];
  const float* qkv_b       = (const float*)d_in[2];
  const float* dw_w        = (const float*)d_in[3];
  const float* dw_b        = (const float*)d_in[4];
  const float* proj_w      = (const float*)d_in[5];
  const float* proj_b      = (const float*)d_in[6];
  const float* temperature = (const float*)d_in[7];
  const float* attn_w      = (const float*)d_in[8];
  float* out = (float*)d_out;

  unsigned short* xT      = (unsigned short*)d_ws;   // 16,777,216 sh
  unsigned short* qkv_wb  = xT + (size_t)16777216;   //     49,152
  unsigned short* proj_wb = qkv_wb + 49152;          //     16,384
  unsigned short* qkvd    = proj_wb + 16384;         // 33,554,432 (q,k only)
  unsigned short* vT      = qkvd + (size_t)33554432; // 16,777,216
  unsigned short* Mb      = vT + (size_t)16777216;   //    524,288
  float* part = (float*)(Mb + 524288);               //  1,048,576 f
  // total ~139.6 MB workspace; no memset needed (part fully overwritten)

  k0_xt    <<<dim3(64, 4, 32),  256, 0, stream>>>(x, xT);
  k0_w     <<<dim3(64),         256, 0, stream>>>(qkv_w, proj_w, qkv_wb, proj_wb);
  k1_qkv_dw<<<dim3(33, 3, 32),  256, 0, stream>>>(xT, qkv_wb, qkv_b, dw_w, dw_b,
                                                  qkvd, vT);
  k3_gram  <<<dim3(4, H_, B_),  256, 0, stream>>>(qkvd, part);
  k45      <<<dim3(B_),         256, 0, stream>>>(part, proj_wb, temperature,
                                                  attn_w, Mb);
  k6_out   <<<dim3(32, B_),     256, 0, stream>>>(vT, Mb, proj_b, out);
}

// Round 4
// 269.718 us; speedup vs baseline: 2.9388x; 1.0820x over previous
//
#include <hip/hip_runtime.h>

#define B_ 32
#define CD 128
#define O3 384
#define N  4096
#define H_ 4
#define C_ 32

typedef __bf16 bf16x8 __attribute__((ext_vector_type(8)));
typedef float floatx4 __attribute__((ext_vector_type(4)));

#define MFMA16(a, b, c) __builtin_amdgcn_mfma_f32_16x16x32_bf16(a, b, c, 0, 0, 0)

__device__ __forceinline__ float b2f(unsigned int u) {   // low 16 bits
  return __builtin_bit_cast(float, u << 16);
}
__device__ __forceinline__ float b2fh(unsigned int u) {  // high 16 bits
  return __builtin_bit_cast(float, u & 0xffff0000u);
}
__device__ __forceinline__ unsigned short f2b(float f) {
  unsigned int bits = __builtin_bit_cast(unsigned int, f);
  unsigned int r = (bits + 0x7FFFu + ((bits >> 16) & 1u)) >> 16;
  return (unsigned short)r;
}

// ---------------------------------------------------------------------------
// K0a: transpose+convert x [b][c][n] fp32 -> xT [b][n][c] bf16.
// ---------------------------------------------------------------------------
__global__ __launch_bounds__(256) void k0_xt(const float* __restrict__ x,
                                             unsigned short* __restrict__ xT)
{
  __shared__ float xt[32 * 68];
  const int t = threadIdx.x;
  const int n0 = blockIdx.x * 64, c0 = blockIdx.y * 32, b = blockIdx.z;
  const float* xb = x + ((size_t)b * CD + c0) * N + n0;
#pragma unroll
  for (int i = 0; i < 2; i++) {
    int f = i * 256 + t;
    int c = f >> 4, n4 = (f & 15) * 4;
    float4 v = *(const float4*)(xb + (size_t)c * N + n4);
    *(float4*)&xt[c * 68 + n4] = v;
  }
  __syncthreads();
  int n = t >> 2, cb = (t & 3) * 8;
  unsigned short tmp[8];
#pragma unroll
  for (int j = 0; j < 8; j++) tmp[j] = f2b(xt[(cb + j) * 68 + n]);
  *(uint4*)(xT + ((size_t)b * N + n0 + n) * CD + c0 + cb) = *(uint4*)tmp;
}

// K0b: qkv_w and proj_w fp32 -> bf16.
__global__ void k0_w(const float* __restrict__ qkv_w,
                     const float* __restrict__ proj_w,
                     unsigned short* __restrict__ qkv_wb,
                     unsigned short* __restrict__ proj_wb)
{
  int e = (blockIdx.x * 256 + threadIdx.x) * 4;
  const float* src; unsigned short* dst; int off;
  if (e < 49152) { src = qkv_w; dst = qkv_wb; off = e; }
  else           { src = proj_w; dst = proj_wb; off = e - 49152; }
  float4 v = *(const float4*)(src + off);
  unsigned short tmp[4] = {f2b(v.x), f2b(v.y), f2b(v.z), f2b(v.w)};
  *(uint2*)(dst + off) = *(uint2*)tmp;
}

// ---------------------------------------------------------------------------
// K1: MFMA GEMM (128o x 124y outputs, 128 staged rows incl. 2+2 halo, K=128)
// + bias + 3-tap depthwise + bias. A-operand (weights) from global per-ks
// (L2-hot, no LDS); LDS = Bs[128][136] only, aliased by bf16 pre-dw tile.
// q,k -> qkvd[b][o2][n]; v -> vT[b][n][c]. grid (34, 3, 32), 256 thr.
// LDS 34,816 B -> 4 blocks/CU.
// ---------------------------------------------------------------------------
__global__ __launch_bounds__(256, 4) void k1_qkv_dw(
    const unsigned short* __restrict__ xT, const unsigned short* __restrict__ qkv_wb,
    const float* __restrict__ qkv_b, const float* __restrict__ dw_w,
    const float* __restrict__ dw_b, unsigned short* __restrict__ qkvd,
    unsigned short* __restrict__ vT)
{
  __shared__ __align__(16) char smem[34816];
  unsigned short* Bs   = (unsigned short*)smem;   // [128][136] staged x rows
  unsigned short* pres = (unsigned short*)smem;   // bf16 pre-dw tile (alias)

  const int t = threadIdx.x;
  const int ytile = blockIdx.x, otile = blockIdx.y, b = blockIdx.z;
  const int obase = otile * 128;
  const int ybase = ytile * 124;                  // first output y (even)
  const int wv = t >> 6, l = t & 63, quad = l >> 4, lm = l & 15;

  // stage B: rows i=0..127 <-> y = ybase-2+i (zero outside [0,N))
#pragma unroll
  for (int i = 0; i < 8; i++) {
    int f = i * 256 + t;
    int row = f >> 4, c8 = (f & 15) * 8;
    int yg = ybase - 2 + row;
    uint4 v = make_uint4(0u, 0u, 0u, 0u);
    if (yg >= 0 && yg < N)
      v = *(const uint4*)(xT + ((size_t)b * N + yg) * CD + c8);
    *(uint4*)&Bs[row * 136 + c8] = v;
  }
  __syncthreads();

  floatx4 acc[2][8];
#pragma unroll
  for (int mt = 0; mt < 2; mt++)
#pragma unroll
    for (int nt = 0; nt < 8; nt++) acc[mt][nt] = (floatx4){0.f, 0.f, 0.f, 0.f};

  const unsigned short* wbase =
      qkv_wb + (size_t)(obase + wv * 32 + lm) * CD + quad * 8;
#pragma unroll
  for (int ks = 0; ks < 4; ks++) {
    bf16x8 a0 = *(const bf16x8*)(wbase + ks * 32);
    bf16x8 a1 = *(const bf16x8*)(wbase + 16 * CD + ks * 32);
#pragma unroll
    for (int nt = 0; nt < 8; nt++) {
      bf16x8 bb = *(const bf16x8*)&Bs[(nt * 16 + lm) * 136 + ks * 32 + quad * 8];
      acc[0][nt] = MFMA16(a0, bb, acc[0][nt]);
      acc[1][nt] = MFMA16(a1, bb, acc[1][nt]);
    }
  }

  if (otile < 2) {
    // ---- q,k: pres[o][j] (j = local row - 1, j in [0,126]), stride 132
    __syncthreads();
#pragma unroll
    for (int mt = 0; mt < 2; mt++)
#pragma unroll
      for (int r = 0; r < 4; r++) {
        int o = wv * 32 + mt * 16 + quad * 4 + r;
        float bias = qkv_b[obase + o];
#pragma unroll
        for (int nt = 0; nt < 8; nt++) {
          int i = nt * 16 + lm;
          if (i >= 1) {
            int yg = ybase - 2 + i;
            pres[o * 132 + (i - 1)] =
                f2b((yg >= 0 && yg < N) ? (acc[mt][nt][r] + bias) : 0.f);
          }
        }
      }
    __syncthreads();
    // y-pair sweep: wave-uniform o, lanes cover 62 aligned pairs
    const int p = t & 63, og = t >> 6;
    const bool ok = (p < 62) && (ybase + 2 * p < N);
    const unsigned int* presu = (const unsigned int*)pres;  // pairs of bf16
    for (int r2 = 0; r2 < 32; r2++) {
      int oo = __builtin_amdgcn_readfirstlane(obase + og * 32 + r2);
      float w0 = dw_w[oo * 9 + 1], w1 = dw_w[oo * 9 + 4],
            w2 = dw_w[oo * 9 + 7], db = dw_b[oo];
      int o = oo - obase;
      unsigned int u0 = presu[(o * 132 >> 1) + p];
      unsigned int u1 = presu[(o * 132 >> 1) + p + 1];
      float v0 = b2f(u0), v1 = b2fh(u0), v2 = b2f(u1), v3 = b2fh(u1);
      float out0 = w0 * v0 + w1 * v1 + w2 * v2 + db;
      float out1 = w0 * v1 + w1 * v2 + w2 * v3 + db;
      unsigned int pk = (unsigned int)f2b(out0) |
                        ((unsigned int)f2b(out1) << 16);
      if (ok)
        *(unsigned int*)(qkvd + ((size_t)b * 256 + oo) * N + ybase + 2 * p) = pk;
    }
  } else {
    // ---- v: pres[i][o], stride 132; per-lane o, sliding window over y
    const int o = t & 127, half = t >> 7;
    const int oo = obase + o;
    const float w0 = dw_w[oo * 9 + 1], w1 = dw_w[oo * 9 + 4],
                w2 = dw_w[oo * 9 + 7], db = dw_b[oo];
    __syncthreads();
#pragma unroll
    for (int mt = 0; mt < 2; mt++)
#pragma unroll
      for (int r = 0; r < 4; r++) {
        int o2 = wv * 32 + mt * 16 + quad * 4 + r;
        float bias = qkv_b[obase + o2];
#pragma unroll
        for (int nt = 0; nt < 8; nt++) {
          int i = nt * 16 + lm;
          int yg = ybase - 2 + i;
          pres[i * 132 + o2] =
              f2b((yg >= 0 && yg < N) ? (acc[mt][nt][r] + bias) : 0.f);
        }
      }
    __syncthreads();
    int i0 = 2 + half * 62;                     // halves: i 2..63, 64..125
    float pm = b2f((unsigned int)pres[(i0 - 1) * 132 + o]);
    float pc = b2f((unsigned int)pres[i0 * 132 + o]);
    for (int i = i0; i < i0 + 62; i++) {
      float pp = b2f((unsigned int)pres[(i + 1) * 132 + o]);
      int yo = ybase - 2 + i;
      if (yo < N) {
        float v = w0 * pm + w1 * pc + w2 * pp + db;
        vT[((size_t)b * N + yo) * CD + o] = f2b(v);
      }
      pm = pc; pc = pp;
    }
  }
}

// ---------------------------------------------------------------------------
// K3: MFMA Gram, fragments loaded straight from global (K-major layout),
// no staging barriers. 32x32 QK^T partial over 1024 n + Q/K norms via
// self-MFMA diagonals. part[b][h][ns][2048]. grid (4, H, B), 256 thr.
// ---------------------------------------------------------------------------
__global__ __launch_bounds__(256, 4) void k3_gram(
    const unsigned short* __restrict__ qkvd, float* __restrict__ part)
{
  __shared__ float red[4 * 8 * 272];   // [wv][tile][row*17+col]
  const int ns = blockIdx.x, h = blockIdx.y, b = blockIdx.z;
  const int t = threadIdx.x;
  const int wv = t >> 6, l = t & 63, quad = l >> 4, lm = l & 15;
  const unsigned short* qb = qkvd + ((size_t)b * 256 + h * C_) * N;
  const unsigned short* kb = qkvd + ((size_t)b * 256 + 128 + h * C_) * N;

  floatx4 acc[8];
#pragma unroll
  for (int i = 0; i < 8; i++) acc[i] = (floatx4){0.f, 0.f, 0.f, 0.f};

  const int nbase = ns * 1024 + wv * 32 + quad * 8;
#pragma unroll
  for (int ch = 0; ch < 8; ch++) {
    int nc = nbase + ch * 128;
    bf16x8 a0 = *(const bf16x8*)(qb + (size_t)lm * N + nc);
    bf16x8 a1 = *(const bf16x8*)(qb + (size_t)(16 + lm) * N + nc);
    bf16x8 b0 = *(const bf16x8*)(kb + (size_t)lm * N + nc);
    bf16x8 b1 = *(const bf16x8*)(kb + (size_t)(16 + lm) * N + nc);
    acc[0] = MFMA16(a0, b0, acc[0]);
    acc[1] = MFMA16(a0, b1, acc[1]);
    acc[2] = MFMA16(a1, b0, acc[2]);
    acc[3] = MFMA16(a1, b1, acc[3]);
    acc[4] = MFMA16(a0, a0, acc[4]);
    acc[5] = MFMA16(a1, a1, acc[5]);
    acc[6] = MFMA16(b0, b0, acc[6]);
    acc[7] = MFMA16(b1, b1, acc[7]);
  }

#pragma unroll
  for (int tl = 0; tl < 8; tl++)
#pragma unroll
    for (int r = 0; r < 4; r++)
      red[wv * 2176 + tl * 272 + (quad * 4 + r) * 17 + lm] = acc[tl][r];
  __syncthreads();

  float* pb = part + ((size_t)(b * H_ + h) * 4 + ns) * 2048;
  for (int e = t; e < 2048; e += 256) {
    int tl = e >> 8, rc = e & 255, row = rc >> 4, col = rc & 15;
    int a = tl * 272 + row * 17 + col;
    float s = red[a] + red[2176 + a] + red[2 * 2176 + a] + red[3 * 2176 + a];
    if (tl < 4) {
      int mt = tl >> 1, nt = tl & 1;
      pb[(mt * 16 + row) * 32 + nt * 16 + col] = s;
    } else if (row == col) {
      if (tl < 6) pb[1024 + (tl - 4) * 16 + row] = s;
      else        pb[1056 + (tl - 6) * 16 + row] = s;
    }
  }
}

// ---------------------------------------------------------------------------
// K45: sum partials, normalize+temperature, exact stable top-k ranks, fold
// 4 masked softmaxes -> AwtT bf16; M = proj_w @ blockdiag(A) via MFMA.
// grid (B), 256 thr.
// ---------------------------------------------------------------------------
__global__ __launch_bounds__(256) void k45(
    const float* __restrict__ part, const unsigned short* __restrict__ proj_wb,
    const float* __restrict__ temperature, const float* __restrict__ attn_w,
    unsigned short* __restrict__ Mb)
{
  __shared__ float La[H_][C_][33];
  __shared__ float sq2[256];
  __shared__ float rn[256];
  __shared__ float exL[H_][C_][33];
  __shared__ unsigned char rkL[H_][C_][C_];
  __shared__ unsigned short AwtT[H_][C_][40];
  const int b = blockIdx.x, t = threadIdx.x;

  const float* pbb = part + (size_t)b * 32768;
  for (int e = t; e < 4 * 2048; e += 256) {
    int h = e >> 11, idx = e & 2047;
    if (idx < 1088) {
      const float* p = pbb + h * 8192 + idx;
      float s = p[0] + p[2048] + p[2 * 2048] + p[3 * 2048];
      if (idx < 1024) La[h][idx >> 5][idx & 31] = s;
      else if (idx < 1056) sq2[h * 32 + (idx - 1024)] = s;
      else sq2[128 + h * 32 + (idx - 1056)] = s;
    }
  }
  __syncthreads();
  rn[t] = 1.f / fmaxf(sqrtf(sq2[t]), 1e-12f);
  __syncthreads();
  for (int e = t; e < 4096; e += 256) {
    int h = e >> 10, i = (e >> 5) & 31, j = e & 31;
    La[h][i][j] *= rn[h * 32 + i] * rn[128 + h * 32 + j] * temperature[h];
  }
  __syncthreads();

  if (t < 128) {
    int h = t >> 5, i = t & 31;
    float m = -1e30f;
    for (int j = 0; j < 32; j++) m = fmaxf(m, La[h][i][j]);
    float S0 = 0.f, S1 = 0.f, S2 = 0.f, S3 = 0.f;
    for (int j = 0; j < 32; j++) {
      float vj = La[h][i][j];
      int r = 0;
      for (int j2 = 0; j2 < 32; j2++) {
        float v2 = La[h][i][j2];
        r += (v2 > vj) || (v2 == vj && j2 < j);
      }
      float e = __expf(vj - m);
      exL[h][i][j] = e;
      rkL[h][i][j] = (unsigned char)r;
      if (r < 16) S0 += e;
      if (r < 21) S1 += e;
      if (r < 24) S2 += e;
      if (r < 25) S3 += e;
    }
    float w0 = attn_w[0] / S0, w1 = attn_w[1] / S1;
    float w2 = attn_w[2] / S2, w3 = attn_w[3] / S3;
    for (int j = 0; j < 32; j++) {
      int r = rkL[h][i][j];
      float cmb = (r < 16 ? w0 : 0.f) + (r < 21 ? w1 : 0.f) +
                  (r < 24 ? w2 : 0.f) + (r < 25 ? w3 : 0.f);
      AwtT[h][j][i] = f2b(exL[h][i][j] * cmb);
    }
  }
  __syncthreads();

  {
    const int wv = t >> 6, l = t & 63, quad = l >> 4, lm = l & 15;
    const int h = wv;
    bf16x8 bfr[2];
#pragma unroll
    for (int jt = 0; jt < 2; jt++)
      bfr[jt] = *(const bf16x8*)&AwtT[h][jt * 16 + lm][quad * 8];
#pragma unroll
    for (int mt = 0; mt < 8; mt++) {
      bf16x8 a = *(const bf16x8*)(proj_wb +
                    (size_t)(mt * 16 + lm) * CD + h * C_ + quad * 8);
#pragma unroll
      for (int jt = 0; jt < 2; jt++) {
        floatx4 acc = (floatx4){0.f, 0.f, 0.f, 0.f};
        acc = MFMA16(a, bfr[jt], acc);
#pragma unroll
        for (int r = 0; r < 4; r++) {
          int row = quad * 4 + r;
          Mb[(size_t)b * 16384 + (mt * 16 + row) * CD + h * C_ + jt * 16 + lm] =
              f2b(acc[r]);
        }
      }
    }
  }
}

// ---------------------------------------------------------------------------
// K6: out[b] = Mb @ V^T + proj_b. A (Mb) per-ks from global (L2-hot);
// LDS = Bs only -> 4 blocks/CU. grid (32, 32), 256 thr.
// ---------------------------------------------------------------------------
__global__ __launch_bounds__(256, 4) void k6_out(
    const unsigned short* __restrict__ vT, const unsigned short* __restrict__ Mb,
    const float* __restrict__ proj_b, float* __restrict__ out)
{
  __shared__ unsigned short Bs[128 * 136];
  const int t = threadIdx.x;
  const int y0 = blockIdx.x * 128, b = blockIdx.y;
  const int wv = t >> 6, l = t & 63, quad = l >> 4, lm = l & 15;

#pragma unroll
  for (int i = 0; i < 8; i++) {
    int f = i * 256 + t;
    int row = f >> 4, c8 = (f & 15) * 8;
    *(uint4*)&Bs[row * 136 + c8] =
        *(const uint4*)(vT + ((size_t)b * N + y0 + row) * CD + c8);
  }
  __syncthreads();

  floatx4 acc[2][8];
#pragma unroll
  for (int mt = 0; mt < 2; mt++)
#pragma unroll
    for (int nt = 0; nt < 8; nt++) acc[mt][nt] = (floatx4){0.f, 0.f, 0.f, 0.f};

  const unsigned short* mbase =
      Mb + (size_t)b * 16384 + (size_t)(wv * 32 + lm) * CD + quad * 8;
#pragma unroll
  for (int ks = 0; ks < 4; ks++) {
    bf16x8 a0 = *(const bf16x8*)(mbase + ks * 32);
    bf16x8 a1 = *(const bf16x8*)(mbase + 16 * CD + ks * 32);
#pragma unroll
    for (int nt = 0; nt < 8; nt++) {
      bf16x8 bb = *(const bf16x8*)&Bs[(nt * 16 + lm) * 136 + ks * 32 + quad * 8];
      acc[0][nt] = MFMA16(a0, bb, acc[0][nt]);
      acc[1][nt] = MFMA16(a1, bb, acc[1][nt]);
    }
  }

#pragma unroll
  for (int mt = 0; mt < 2; mt++)
#pragma unroll
    for (int r = 0; r < 4; r++) {
      int o = wv * 32 + mt * 16 + quad * 4 + r;
      float pb = proj_b[o];
#pragma unroll
      for (int nt = 0; nt < 8; nt++) {
        int y = y0 + nt * 16 + lm;
        out[((size_t)b * CD + o) * N + y] = acc[mt][nt][r] + pb;
      }
    }
}

extern "C" void kernel_launch(void* const* d_in, const int* in_sizes, int n_in,
                              void* d_out, int out_size, void* d_ws, size_t ws_size,
                              hipStream_t stream)
{
  (void)in_sizes; (void)n_in; (void)out_size; (void)ws_size;
  const float* x           = (const float*)d_in[0];
  const float* qkv_w       = (const float*)d_in[1];
  const float* qkv_b       = (const float*)d_in[2];
  const float* dw_w        = (const float*)d_in[3];
  const float* dw_b        = (const float*)d_in[4];
  const float* proj_w      = (const float*)d_in[5];
  const float* proj_b      = (const float*)d_in[6];
  const float* temperature = (const float*)d_in[7];
  const float* attn_w      = (const float*)d_in[8];
  float* out = (float*)d_out;

  unsigned short* xT      = (unsigned short*)d_ws;   // 16,777,216 sh
  unsigned short* qkv_wb  = xT + (size_t)16777216;   //     49,152
  unsigned short* proj_wb = qkv_wb + 49152;          //     16,384
  unsigned short* qkvd    = proj_wb + 16384;         // 33,554,432 (q,k)
  unsigned short* vT      = qkvd + (size_t)33554432; // 16,777,216
  unsigned short* Mb      = vT + (size_t)16777216;   //    524,288
  float* part = (float*)(Mb + 524288);               //  1,048,576 f

  k0_xt    <<<dim3(64, 4, 32),  256, 0, stream>>>(x, xT);
  k0_w     <<<dim3(64),         256, 0, stream>>>(qkv_w, proj_w, qkv_wb, proj_wb);
  k1_qkv_dw<<<dim3(34, 3, 32),  256, 0, stream>>>(xT, qkv_wb, qkv_b, dw_w, dw_b,
                                                  qkvd, vT);
  k3_gram  <<<dim3(4, H_, B_),  256, 0, stream>>>(qkvd, part);
  k45      <<<dim3(B_),         256, 0, stream>>>(part, proj_wb, temperature,
                                                  attn_w, Mb);
  k6_out   <<<dim3(32, B_),     256, 0, stream>>>(vT, Mb, proj_b, out);
}